// Round 12
// baseline (365.939 us; speedup 1.0000x reference)
//
#include <hip/hip_runtime.h>

typedef __bf16 bf16;
typedef __attribute__((ext_vector_type(2))) __bf16 bf16x2;
typedef __attribute__((ext_vector_type(4))) __bf16 bf16x4;
typedef __attribute__((ext_vector_type(8))) __bf16 bf16x8;
typedef __attribute__((ext_vector_type(4))) float f32x4;

#define DEVINL __device__ __forceinline__

typedef __attribute__((address_space(1))) void gvoid_t;
typedef __attribute__((address_space(3))) void lvoid_t;

DEVINL void async_ld16(const void* g, void* l) {
    __builtin_amdgcn_global_load_lds((gvoid_t*)g, (lvoid_t*)l, 16, 0, 0);
}

DEVINL void wait_vm8()   { asm volatile("s_waitcnt vmcnt(8)" ::: "memory"); }
DEVINL void wait_vm4()   { asm volatile("s_waitcnt vmcnt(4)" ::: "memory"); }
DEVINL void wait_vm0()   { asm volatile("s_waitcnt vmcnt(0)" ::: "memory"); }
DEVINL void wait_lgkm0() { asm volatile("s_waitcnt lgkmcnt(0)" ::: "memory");
                           __builtin_amdgcn_sched_barrier(0); }  // rule 18
DEVINL void barrier_()   { __builtin_amdgcn_s_barrier(); }

// ============================================================================
// 8-wave 256x256 GEMM, 2Mx4N, QUAD-BUFFERED K-steps (BK=32) with counted
// vmcnt (T3+T4 pipeline).
// r10 FAILED on a buffer-stride bug: step-buffer = 32 KB (16384 bf16:
// A[256x32] 16KB + B[256x32] 16KB) but the code used stride 8192 bf16 with
// B at +4096 -> B overlapped A rows 128-255 and buffers overlapped each
// other. Fixed: stride (s&3)*16384, B-half at +8192. Schedule unchanged:
//   LDS = 4 step-buffers x 32KB = 128 KB; prefetch distance = 3 steps.
//   Steady-state gate = vmcnt(8): steps s+2,s+3 (8 loads) in flight, step
//   s+1 retired. Tail degrades 8 -> 4 -> 0. Never vm0 mid-loop.
// Per K-step s (2 phases, 32 MFMA/wave):
//   p0: LDB(s)+LDA(s,lo) [8 ds_read]; STAGE_A(s+3); BAR; lgkm0; MM(lo); BAR
//   p1: LDA(s,hi) [4];  STAGE_B(s+3); [vm gate]; BAR; lgkm0; MM(hi); BAR
// Gate math at p1(s) after STAGE_B(s+3): outstanding = steps s+1..s+3
// (<NS) x 4 loads; need step s+1 retired -> vm8 / vm4 (s+3==NS) / vm0
// (s+2==NS) / none (s==NS-1).
// WAR: STAGE_X(s+3) at step s writes buffer (s-1)&3; step s-1's last reads
// completed (lgkm0) before the barrier preceding this phase. Safe.
// Buffer layout: [256 rows][4 granules 16B], swizzle (r,g) holds global
// granule g^(r&3) — source pre-swizzled, LDS dest linear.
// Register budget: acc[8][4]=128 AGPR; bfr[4]+af[4]=32 + addressing ~100
// arch < 128 (512-thr block = 2 waves/SIMD -> 256 total regs/wave).
// MODE 0: A gathered from obj/pred via edges (K=1536, S|P|O), out -> Dbf
// MODE 1: wave-uniform split by col: <512 Dbf | <1024 Df(f32) | else Dbf2
// Epilogue: r9's validated 2Mx4N per-wave 16KB LDS C-stage.
// ============================================================================
template<int MODE>
__global__ __launch_bounds__(512, 1) void gemm8_k(
    const bf16* __restrict__ A, const bf16* __restrict__ Bt,
    const float* __restrict__ bias, bf16* __restrict__ Dbf,
    float* __restrict__ Df, bf16* __restrict__ Dbf2,
    const int* __restrict__ edges, const bf16* __restrict__ obj,
    const bf16* __restrict__ pred, int K, int NBN)
{
    const int tid = threadIdx.x;
    const int id = blockIdx.x;
    const int bn = (id >> 3) % NBN;
    const int bm = (id & 7) + 8 * ((id >> 3) / NBN);

    __shared__ __align__(16) bf16 lds[4 * 16384];   // 128 KiB: 4 x 32KB buffers

    const int gA = tid & 3;        // granule slot within 32-col row
    const int rowA = tid >> 2;     // 0..127; thread covers rowA, rowA+128

    unsigned offS[2], offP[2], offO[2], offA[2], offB[2];
#pragma unroll
    for (int i = 0; i < 2; i++) {
        int r = rowA + i * 128;
        int gr = bm * 256 + r;
        if (MODE == 0) {
            int b = gr >> 9;  // T = 512
            int s = edges[gr * 3 + 0] & 255;
            int o = edges[gr * 3 + 2] & 255;
            offS[i] = (unsigned)(b * 256 + s) * 512u;
            offP[i] = (unsigned)gr * 512u;
            offO[i] = (unsigned)(b * 256 + o) * 512u;
        } else {
            offA[i] = (unsigned)gr * (unsigned)K;
        }
        offB[i] = (unsigned)(bn * 256 + r) * (unsigned)K;
    }

    // stage A-slice of step ss: 2 x global_load_lds per thread
    auto STAGE_A = [&](int ss) {
        bf16* ldst = lds + (ss & 3) * 16384;
#pragma unroll
        for (int i = 0; i < 2; i++) {
            int row = rowA + i * 128;
            int gsrc = gA ^ (row & 3);
            const bf16* gp;
            if (MODE == 0) {
                int region = ss >> 4;   // (ss*32)/512, wave-uniform
                unsigned col = (unsigned)((ss & 15) * 32 + gsrc * 8);
                if (region == 0)      gp = obj + offS[i] + col;
                else if (region == 1) gp = pred + offP[i] + col;
                else                  gp = obj + offO[i] + col;
            } else {
                gp = A + offA[i] + (unsigned)(ss * 32 + gsrc * 8);
            }
            async_ld16(gp, ldst + (tid + i * 512) * 8);
        }
    };
    auto STAGE_B = [&](int ss) {
        bf16* ldst = lds + (ss & 3) * 16384 + 8192;
#pragma unroll
        for (int i = 0; i < 2; i++) {
            int row = rowA + i * 128;
            int gsrc = gA ^ (row & 3);
            async_ld16(Bt + offB[i] + (unsigned)(ss * 32 + gsrc * 8),
                       ldst + (tid + i * 512) * 8);
        }
    };

    f32x4 acc[8][4];
    const f32x4 zero4 = {0.f, 0.f, 0.f, 0.f};
#pragma unroll
    for (int i = 0; i < 8; i++)
#pragma unroll
        for (int j = 0; j < 4; j++) acc[i][j] = zero4;

    const int wave = tid >> 6, lane = tid & 63;
    const int wm = wave >> 2, wn = wave & 3;   // 2M x 4N
    const int lq = lane >> 4, lr = lane & 15;

    bf16x8 bfr[4];   // wave's 64 C-cols x K=32; lives for the whole step
    bf16x8 af[4];    // one 64-row M-half x K=32; reloaded per phase

    auto LDB = [&](int ss) {
        const bf16* base = lds + (ss & 3) * 16384 + 8192;
#pragma unroll
        for (int n = 0; n < 4; n++) {
            int rr = wn * 64 + n * 16 + lr;
            int g = lq ^ (rr & 3);
            bfr[n] = *(const bf16x8*)(base + (rr * 4 + g) * 8);
        }
    };
    auto LDA = [&](int ss, int h) {
        const bf16* base = lds + (ss & 3) * 16384;
#pragma unroll
        for (int mi = 0; mi < 4; mi++) {
            int rr = wm * 128 + h * 64 + mi * 16 + lr;
            int g = lq ^ (rr & 3);
            af[mi] = *(const bf16x8*)(base + (rr * 4 + g) * 8);
        }
    };
    auto MM = [&](int h) {
        __builtin_amdgcn_s_setprio(1);
#pragma unroll
        for (int mi = 0; mi < 4; mi++)
#pragma unroll
            for (int n = 0; n < 4; n++)
                acc[h * 4 + mi][n] = __builtin_amdgcn_mfma_f32_16x16x32_bf16(
                    bfr[n], af[mi], acc[h * 4 + mi][n], 0, 0, 0);
        __builtin_amdgcn_s_setprio(0);
    };

    const int NS = K >> 5;   // K-steps of 32 (>= 16 for all our shapes)
    // prologue: stage steps 0,1,2; gate step 0 (leave steps 1,2 = 8 in flight)
    STAGE_A(0); STAGE_B(0);
    STAGE_A(1); STAGE_B(1);
    STAGE_A(2); STAGE_B(2);
    wait_vm8();
    barrier_();

    for (int s = 0; s < NS; ++s) {
        const bool pf = (s + 3 < NS);
        // ---- p0: reads of step s + stage A(s+3) ----
        LDB(s); LDA(s, 0);
        if (pf) STAGE_A(s + 3);
        barrier_();
        wait_lgkm0();
        MM(0);
        barrier_();
        // ---- p1: reads + stage B(s+3) + counted gate for step s+1 ----
        LDA(s, 1);
        if (pf) STAGE_B(s + 3);
        if (pf)                wait_vm8();
        else if (s + 3 == NS)  wait_vm4();
        else if (s + 2 == NS)  wait_vm0();
        // s == NS-1: nothing outstanding
        barrier_();
        wait_lgkm0();
        MM(1);
        barrier_();
    }

    // ---- epilogue (validated 2Mx4N scheme): per-wave 16KB LDS C-stage ----
    const int rowbase = bm * 256 + wm * 128;
    const int cb0 = bn * 256 + wn * 64;
    const bool f32p = (MODE == 1) && (cb0 >= 512) && (cb0 < 1024);

    if (!f32p) {
        bf16* cw = lds + wave * 8192;   // [128 rows][64 cols] bf16
        bf16* outp; int cb;
        if (MODE == 1) {
            if (cb0 < 512) { outp = Dbf;  cb = cb0; }
            else           { outp = Dbf2; cb = cb0 - 1024; }
        } else { outp = Dbf; cb = cb0; }
#pragma unroll
        for (int ni = 0; ni < 4; ++ni) {
            const f32x4 bv = *(const f32x4*)(bias + cb0 + ni * 16 + lq * 4);
#pragma unroll
            for (int mi = 0; mi < 8; ++mi) {
                f32x4 v = acc[mi][ni];
                int row = mi * 16 + lr;
                int sl = (ni * 2 + (lq >> 1)) ^ (row & 7);
                bf16x4 o4;
#pragma unroll
                for (int r = 0; r < 4; r++) {
                    float x = v[r] + bv[r];
                    o4[r] = (bf16)(x > 0.f ? x : 0.f);
                }
                *(bf16x4*)(cw + row * 64 + sl * 8 + (lq & 1) * 4) = o4;
            }
        }
#pragma unroll
        for (int it = 0; it < 16; ++it) {
            int g = it * 64 + lane;
            int row = g >> 3, k = g & 7;
            bf16x8 v = *(const bf16x8*)(cw + row * 64 + ((k ^ (row & 7)) * 8));
            *(bf16x8*)(outp + (unsigned)(rowbase + row) * 512u + cb + k * 8) = v;
        }
    } else {
        float* cwf = (float*)(lds + wave * 8192);   // [64 rows][64 f32] x2
        const int cbf = cb0 - 512;
#pragma unroll
        for (int mh = 0; mh < 2; ++mh) {
#pragma unroll
            for (int ni = 0; ni < 4; ++ni) {
                const f32x4 bv = *(const f32x4*)(bias + cb0 + ni * 16 + lq * 4);
#pragma unroll
                for (int mi2 = 0; mi2 < 4; ++mi2) {
                    f32x4 v = acc[mh * 4 + mi2][ni];
                    int row = mi2 * 16 + lr;   // 0..63
                    int s16 = ni * 4 + lq;
                    int sl = (s16 & 8) | ((s16 & 7) ^ (row & 7));
                    f32x4 x;
#pragma unroll
                    for (int r = 0; r < 4; r++) {
                        float tt = v[r] + bv[r];
                        x[r] = tt > 0.f ? tt : 0.f;
                    }
                    *(f32x4*)(cwf + row * 64 + sl * 4) = x;
                }
            }
#pragma unroll
            for (int it = 0; it < 16; ++it) {
                int flat = it * 64 + lane;
                int row = flat >> 4, k = flat & 15;
                int kk = (k & 8) | ((k & 7) ^ (row & 7));
                f32x4 v = *(const f32x4*)(cwf + row * 64 + kk * 4);
                *(f32x4*)(Df + (unsigned)(rowbase + mh * 64 + row) * 512u
                          + cbf + k * 4) = v;
            }
            if (mh == 0) wait_lgkm0();  // WAR: half1 writes reuse half0 space
        }
    }
}

// ============================================================================
// Verified 128x128 4-wave kernel (round-4), for the small gemms 3/4.
// MODE 2: plain -> Dbf.  MODE 3: plain -> Df (f32)
// ============================================================================
template<int MODE, int NBN>
__global__ __launch_bounds__(256, 2) void gemm_k(
    const bf16* __restrict__ A, const bf16* __restrict__ Bt,
    const float* __restrict__ bias, bf16* __restrict__ Dbf,
    float* __restrict__ Df, int K)
{
    const int tid = threadIdx.x;
    const int id = blockIdx.x;
    const int bn = (id >> 3) % NBN;
    const int bm = (id & 7) + 8 * ((id >> 3) / NBN);

    __shared__ __align__(16) bf16 lds[2 * 128 * 64];
    bf16* ldsA = lds;
    bf16* ldsB = lds + 128 * 64;

    const int g_slot = tid & 7;
    const int row0 = tid >> 3;

    unsigned offA[4], offB[4];
#pragma unroll
    for (int i = 0; i < 4; i++) {
        int r = row0 + 32 * i;
        offA[i] = (unsigned)(bm * 128 + r) * (unsigned)K;
        offB[i] = (unsigned)(bn * 128 + r) * (unsigned)K;
    }

    f32x4 acc[4][4];
    const f32x4 zero4 = {0.f, 0.f, 0.f, 0.f};
#pragma unroll
    for (int i = 0; i < 4; i++)
#pragma unroll
        for (int j = 0; j < 4; j++) acc[i][j] = zero4;

    const int wave = tid >> 6;
    const int lane = tid & 63;
    const int wr = (wave >> 1) * 64;
    const int wc = (wave & 1) * 64;
    const int lq = lane >> 4;
    const int lr = lane & 15;

    const int KT = K >> 6;
    for (int kt = 0; kt < KT; ++kt) {
        __syncthreads();
#pragma unroll
        for (int i = 0; i < 4; i++) {
            int r = row0 + 32 * i;
            int gsrc = g_slot ^ (r & 7);
            async_ld16(A + offA[i] + (unsigned)(kt * 64 + gsrc * 8),
                       ldsA + (tid + i * 256) * 8);
        }
#pragma unroll
        for (int i = 0; i < 4; i++) {
            int r = row0 + 32 * i;
            int gsrc = g_slot ^ (r & 7);
            async_ld16(Bt + offB[i] + (unsigned)(kt * 64 + gsrc * 8),
                       ldsB + (tid + i * 256) * 8);
        }
        __syncthreads();

#pragma unroll
        for (int ks = 0; ks < 2; ++ks) {
            bf16x8 af[4], bfr[4];
#pragma unroll
            for (int mi = 0; mi < 4; ++mi) {
                int r = wr + mi * 16 + lr;
                int g = (ks * 4 + lq) ^ (r & 7);
                af[mi] = *(const bf16x8*)(ldsA + (r * 8 + g) * 8);
            }
#pragma unroll
            for (int ni = 0; ni < 4; ++ni) {
                int r = wc + ni * 16 + lr;
                int g = (ks * 4 + lq) ^ (r & 7);
                bfr[ni] = *(const bf16x8*)(ldsB + (r * 8 + g) * 8);
            }
#pragma unroll
            for (int mi = 0; mi < 4; ++mi)
#pragma unroll
                for (int ni = 0; ni < 4; ++ni)
                    acc[mi][ni] = __builtin_amdgcn_mfma_f32_16x16x32_bf16(
                        bfr[ni], af[mi], acc[mi][ni], 0, 0, 0);
        }
    }

    __syncthreads();
    const int rb = bm * 128 + wr;

    if (MODE == 2) {
        bf16* cw = lds + wave * 4096;
        const int cb = bn * 128 + wc;
#pragma unroll
        for (int ni = 0; ni < 4; ++ni) {
            const f32x4 bv = *(const f32x4*)(bias + cb + ni * 16 + lq * 4);
#pragma unroll
            for (int mi = 0; mi < 4; ++mi) {
                f32x4 v = acc[mi][ni];
                int row = mi * 16 + lr;
                int sl = (ni * 2 + (lq >> 1)) ^ (row & 7);
                bf16x4 o4;
#pragma unroll
                for (int r = 0; r < 4; r++) {
                    float t = v[r] + bv[r];
                    o4[r] = (bf16)(t > 0.f ? t : 0.f);
                }
                *(bf16x4*)(cw + row * 64 + sl * 8 + (lq & 1) * 4) = o4;
            }
        }
#pragma unroll
        for (int it = 0; it < 8; ++it) {
            int g = it * 64 + lane;
            int row = g >> 3, k = g & 7;
            bf16x8 v = *(const bf16x8*)(cw + row * 64 + ((k ^ (row & 7)) * 8));
            *(bf16x8*)(Dbf + (unsigned)(rb + row) * 512u + cb + k * 8) = v;
        }
    } else {
        float* cwf = (float*)lds + wave * 2048;
        const int cbf = bn * 128 + wc;
#pragma unroll
        for (int half = 0; half < 2; ++half) {
#pragma unroll
            for (int ni = 0; ni < 4; ++ni) {
                const f32x4 bv = *(const f32x4*)(bias + cbf + ni * 16 + lq * 4);
#pragma unroll
                for (int mi2 = 0; mi2 < 2; ++mi2) {
                    f32x4 v = acc[half * 2 + mi2][ni];
                    int row = mi2 * 16 + lr;
                    int s16 = ni * 4 + lq;
                    int sl = (s16 & 8) | ((s16 & 7) ^ (row & 7));
                    f32x4 x;
#pragma unroll
                    for (int r = 0; r < 4; r++) {
                        float t = v[r] + bv[r];
                        x[r] = t > 0.f ? t : 0.f;
                    }
                    *(f32x4*)(cwf + row * 64 + sl * 4) = x;
                }
            }
#pragma unroll
            for (int it = 0; it < 8; ++it) {
                int g = it * 64 + lane;
                int row = g >> 4, k = g & 15;
                int kk = (k & 8) | ((k & 7) ^ (row & 7));
                f32x4 v = *(const f32x4*)(cwf + row * 64 + kk * 4);
                *(f32x4*)(Df + (unsigned)(rb + half * 32 + row) * 512u + cbf + k * 4) = v;
            }
        }
    }
}

// Fused preprocessing: cvt obj/pred f32->bf16 + 4 weight transposes
__global__ void pre_k(const float4* __restrict__ o, const float4* __restrict__ p,
                      bf16x4* __restrict__ ob, bf16x4* __restrict__ pb,
                      const float* __restrict__ w1, bf16* __restrict__ w1t,
                      const float* __restrict__ w2, bf16* __restrict__ w2t,
                      const float* __restrict__ w3, bf16* __restrict__ w3t,
                      const float* __restrict__ w4, bf16* __restrict__ w4t) {
    __shared__ float tile[32][33];
    int blk = blockIdx.x;
    int t = threadIdx.x;
    if (blk >= 24576) {
        int id = blk - 24576;
        const float* src; bf16* dst; int R, C, bx, by;
        if (id < 768)       { src = w1; dst = w1t; R = 1536; C = 512;  bx = id % 16; by = id / 16; }
        else if (id < 1536) { id -= 768;  src = w2; dst = w2t; R = 512; C = 1536; bx = id % 48; by = id / 48; }
        else if (id < 1792) { id -= 1536; src = w3; dst = w3t; R = 512; C = 512;  bx = id % 16; by = id / 16; }
        else                { id -= 1792; src = w4; dst = w4t; R = 512; C = 512;  bx = id % 16; by = id / 16; }
        int c0 = bx * 32, r0 = by * 32;
        int tx = t & 31, ty = t >> 5;
#pragma unroll
        for (int i = 0; i < 4; i++)
            tile[ty + i * 8][tx] = src[(size_t)(r0 + ty + i * 8) * C + c0 + tx];
        __syncthreads();
#pragma unroll
        for (int i = 0; i < 4; i++)
            dst[(size_t)(c0 + ty + i * 8) * R + r0 + tx] = (bf16)tile[tx][ty + i * 8];
        return;
    }
    int i = blk * 256 + t;
    if (i < 2097152) {
        float4 v = o[i];
        bf16x4 r = { (bf16)v.x, (bf16)v.y, (bf16)v.z, (bf16)v.w };
        ob[i] = r;
    } else {
        int j = i - 2097152;
        float4 v = p[j];
        bf16x4 r = { (bf16)v.x, (bf16)v.y, (bf16)v.z, (bf16)v.w };
        pb[j] = r;
    }
}

// Self-contained scatter-mean pooling (one block per (b,n))
__global__ __launch_bounds__(256) void pool3_k(
    const int* __restrict__ edges,
    const bf16* __restrict__ new_s, const bf16* __restrict__ new_o,
    bf16* __restrict__ out)
{
    __shared__ int ent[1024];
    __shared__ int ec;
    const int idx = blockIdx.x;
    const int b = idx >> 8, n = idx & 255;
    const int t = threadIdx.x;
    if (t == 0) ec = 0;
    __syncthreads();
#pragma unroll
    for (int e0 = 0; e0 < 2; e0++) {
        int row = b * 512 + t + e0 * 256;
        int s = edges[row * 3 + 0] & 255;
        int o = edges[row * 3 + 2] & 255;
        if (s == n) { int ps = atomicAdd(&ec, 1); ent[ps] = row << 1; }
        if (o == n) { int po = atomicAdd(&ec, 1); ent[po] = (row << 1) | 1; }
    }
    __syncthreads();
    const int c = ec;
    float a0 = 0.f, a1 = 0.f;
    for (int j = 0; j < c; ++j) {
        int v = ent[j];
        const bf16x2* rp = (const bf16x2*)(((v & 1) ? new_o : new_s) +
                                           (unsigned)(v >> 1) * 512u);
        bf16x2 w = rp[t];
        a0 += (float)w[0];
        a1 += (float)w[1];
    }
    float inv = 1.f / (float)(c > 1 ? c : 1);
    bf16x2 o2 = { (bf16)(a0 * inv), (bf16)(a1 * inv) };
    *(bf16x2*)(out + (unsigned)idx * 512u + (unsigned)(t * 2)) = o2;
}

extern "C" void kernel_launch(void* const* d_in, const int* in_sizes, int n_in,
                              void* d_out, int out_size, void* d_ws, size_t ws_size,
                              hipStream_t stream) {
    const float* obj_f  = (const float*)d_in[0];
    const float* pred_f = (const float*)d_in[1];
    const int*   edges  = (const int*)d_in[2];
    const float* w1 = (const float*)d_in[3];
    const float* b1 = (const float*)d_in[4];
    const float* w2 = (const float*)d_in[5];
    const float* b2 = (const float*)d_in[6];
    const float* w3 = (const float*)d_in[7];
    const float* b3 = (const float*)d_in[8];
    const float* w4 = (const float*)d_in[9];
    const float* b4 = (const float*)d_in[10];

    // workspace layout — 88 MB
    char* ws = (char*)d_ws;
    bf16* obj_bf  = (bf16*)(ws + 0);            // 16 MB   [dead after gemm1]
    bf16* pred_bf = (bf16*)(ws + 16777216);     // 32 MB   [dead after gemm1]
    bf16* new_s   = (bf16*)(ws + 0);            // 32 MB   overlays obj/pred
    bf16* w1t = (bf16*)(ws + 50331648);         // 512 x 1536
    bf16* w2t = (bf16*)(ws + 51904512);         // 1536 x 512
    bf16* w3t = (bf16*)(ws + 53477376);         // 512 x 512
    bf16* w4t = (bf16*)(ws + 54001664);         // 512 x 512
    bf16* hid = (bf16*)(ws + 54525952);         // 32768 x 512 (32 MB)
    bf16* pooled_bf = hid;                      // 16 MB, reuse after gemm2
    bf16* h2  = (bf16*)(ws + 71303168);         // 16 MB

    float* out_obj = (float*)d_out;             // 64*256*512 f32
    float* out_p   = (float*)d_out + 8388608;   // 64*512*512 f32
    bf16* new_o    = (bf16*)d_out;              // scratch; overwritten by gemm4

    pre_k<<<26624, 256, 0, stream>>>((const float4*)obj_f, (const float4*)pred_f,
                                     (bf16x4*)obj_bf, (bf16x4*)pred_bf,
                                     w1, w1t, w2, w2t, w3, w3t, w4, w4t);

    // gemm1: gathered [obj[s]|pred|obj[o]] (K=1536) -> hid   (quad-buffered)
    gemm8_k<0><<<256, 512, 0, stream>>>(
        nullptr, w1t, b1, hid, nullptr, nullptr, edges, obj_bf, pred_bf,
        1536, 2);

    // gemm2: hid @ w2t -> new_s | out_p | new_o              (quad-buffered)
    gemm8_k<1><<<768, 512, 0, stream>>>(
        hid, w2t, b2, new_s, out_p, new_o, nullptr, nullptr, nullptr,
        512, 6);

    pool3_k<<<16384, 256, 0, stream>>>(edges, new_s, new_o, pooled_bf);

    // gemm3: pooled @ w3t -> h2   (128x128 path)
    gemm_k<2, 4><<<512, 256, 0, stream>>>(pooled_bf, w3t, b3, h2, nullptr, 512);

    // gemm4: h2 @ w4t -> out_obj (f32)
    gemm_k<3, 4><<<512, 256, 0, stream>>>(h2, w4t, b4, nullptr, out_obj, 512);
}

// Round 13
// 348.885 us; speedup vs baseline: 1.0489x; 1.0489x over previous
//
#include <hip/hip_runtime.h>

typedef __bf16 bf16;
typedef __attribute__((ext_vector_type(2))) __bf16 bf16x2;
typedef __attribute__((ext_vector_type(4))) __bf16 bf16x4;
typedef __attribute__((ext_vector_type(8))) __bf16 bf16x8;
typedef __attribute__((ext_vector_type(4))) float f32x4;

#define DEVINL __device__ __forceinline__

typedef __attribute__((address_space(1))) void gvoid_t;
typedef __attribute__((address_space(3))) void lvoid_t;

DEVINL void async_ld16(const void* g, void* l) {
    __builtin_amdgcn_global_load_lds((gvoid_t*)g, (lvoid_t*)l, 16, 0, 0);
}

DEVINL void wait_vm0()   { asm volatile("s_waitcnt vmcnt(0)" ::: "memory"); }
DEVINL void wait_lgkm0() { asm volatile("s_waitcnt lgkmcnt(0)" ::: "memory");
                           __builtin_amdgcn_sched_barrier(0); }
DEVINL void barrier_()   { __builtin_amdgcn_s_barrier();
                           __builtin_amdgcn_sched_barrier(0); }

// ============================================================================
// 8-wave 256x256 GEMM, 4-phase, 2Mx4N wave layout — BEST VERIFIED (r10:
// 350.99 us total, gemm ~74 us, MfmaUtil 28%, VGPR 100, no spill).
// Post-mortem record (why this shape, and why no further): seven variants —
// 2-barrier 128², exposed/hidden 4-phase, 1Mx8N, 2Mx4N dbuf-vm0, quad-buffer
// counted-vmcnt(8) — ALL land at 25-29% MfmaUtil / ~74 us on these shapes
// (K=512/1536 -> 8-24 K-tiles, split epilogues, 1 blk/CU). Latency-margin
// (r11) and LDS-BW (r9) hypotheses both falsified by counters. This is the
// demonstrated structural ceiling for this problem in this harness.
// Register discipline: JIT loads — bfr[4] lives one kstep, af[4] one phase;
// acc[8][4]=128 AGPR; arch ~100 < 128 (512-thr block = 2 waves/SIMD).
// Phases per K-tile t: p0=(ks0,Mlo) p1=(ks0,Mhi) p2=(ks1,Mlo) p3=(ks1,Mhi);
// stages of t+1: A at p0, B at p1; single vm0 at p3 (late-issued drain).
// LDS = 8 half-slots x 16KB: slot = (t&1)*4 + kind,
//   kind: 0=A rows[0,128), 1=A rows[128,256), 2=B rows[0,128), 3=B rows[128,256)
// Half-slot: [128 rows][8 granules 16B], swizzled: (r,g) holds granule g^(r&7).
// MODE 0: A gathered from obj/pred via edges (K=1536, S|P|O), out -> Dbf
// MODE 1: wave-uniform split by col: <512 Dbf | <1024 Df(f32) | else Dbf2
// Epilogue: validated 2Mx4N per-wave 16KB LDS C-stage, full-line copy-out.
// ============================================================================
template<int MODE>
__global__ __launch_bounds__(512, 1) void gemm8_k(
    const bf16* __restrict__ A, const bf16* __restrict__ Bt,
    const float* __restrict__ bias, bf16* __restrict__ Dbf,
    float* __restrict__ Df, bf16* __restrict__ Dbf2,
    const int* __restrict__ edges, const bf16* __restrict__ obj,
    const bf16* __restrict__ pred, int K, int NBN)
{
    const int tid = threadIdx.x;
    const int id = blockIdx.x;
    const int bn = (id >> 3) % NBN;
    const int bm = (id & 7) + 8 * ((id >> 3) / NBN);

    __shared__ __align__(16) bf16 lds[8 * 8192];   // 128 KiB

    const int g_slot = tid & 7;
    const int row0 = tid >> 3;   // 0..63

    // staged rows per thread: hi = h*2+i -> row (h*128 + i*64 + row0)
    unsigned offS[4], offP[4], offO[4], offA[4], offB[4];
#pragma unroll
    for (int hi = 0; hi < 4; hi++) {
        int r = (hi >> 1) * 128 + (hi & 1) * 64 + row0;
        int gr = bm * 256 + r;
        if (MODE == 0) {
            int b = gr >> 9;  // T = 512
            int s = edges[gr * 3 + 0] & 255;
            int o = edges[gr * 3 + 2] & 255;
            offS[hi] = (unsigned)(b * 256 + s) * 512u;
            offP[hi] = (unsigned)gr * 512u;
            offO[hi] = (unsigned)(b * 256 + o) * 512u;
        } else {
            offA[hi] = (unsigned)gr * (unsigned)K;
        }
        offB[hi] = (unsigned)(bn * 256 + r) * (unsigned)K;
    }

    auto STAGE = [&](int tt, int kind) {
        bf16* ldst = lds + ((tt & 1) * 4 + kind) * 8192;
        int h = kind & 1;
#pragma unroll
        for (int i = 0; i < 2; i++) {
            int r = i * 64 + row0;
            int gsrc = g_slot ^ (r & 7);
            int hi = h * 2 + i;
            const bf16* gp;
            if (kind < 2) {
                if (MODE == 0) {
                    int region = tt >> 3;  // wave-uniform
                    unsigned col = (unsigned)((tt & 7) * 64 + gsrc * 8);
                    if (region == 0)      gp = obj + offS[hi] + col;
                    else if (region == 1) gp = pred + offP[hi] + col;
                    else                  gp = obj + offO[hi] + col;
                } else {
                    gp = A + offA[hi] + (unsigned)(tt * 64 + gsrc * 8);
                }
            } else {
                gp = Bt + offB[hi] + (unsigned)(tt * 64 + gsrc * 8);
            }
            async_ld16(gp, ldst + (tid + i * 512) * 8);
        }
    };

    f32x4 acc[8][4];
    const f32x4 zero4 = {0.f, 0.f, 0.f, 0.f};
#pragma unroll
    for (int i = 0; i < 8; i++)
#pragma unroll
        for (int j = 0; j < 4; j++) acc[i][j] = zero4;

    const int wave = tid >> 6, lane = tid & 63;
    const int wm = wave >> 2, wn = wave & 3;   // 2M x 4N
    const int lq = lane >> 4, lr = lane & 15;

    bf16x8 bfr[4];   // wave's 64 cols, one kstep (K=32); live for 2 phases
    bf16x8 af[4];    // one 64-row M-half, one kstep; reloaded per phase

    auto LDB = [&](int tt, int ks) {
        const bf16* base = lds + ((tt & 1) * 4 + 2 + (wn >> 1)) * 8192;
#pragma unroll
        for (int n = 0; n < 4; n++) {
            int rr = (wn & 1) * 64 + n * 16 + lr;   // local row in B half-slot
            int g = (ks * 4 + lq) ^ (rr & 7);
            bfr[n] = *(const bf16x8*)(base + (rr * 8 + g) * 8);
        }
    };
    auto LDA = [&](int tt, int ks, int h) {
        const bf16* base = lds + ((tt & 1) * 4 + wm) * 8192;
#pragma unroll
        for (int mi = 0; mi < 4; mi++) {
            int rr = (h * 4 + mi) * 16 + lr;        // local row in A half-slot
            int g = (ks * 4 + lq) ^ (rr & 7);
            af[mi] = *(const bf16x8*)(base + (rr * 8 + g) * 8);
        }
    };
    auto MM = [&](int h) {
        __builtin_amdgcn_s_setprio(1);
#pragma unroll
        for (int mi = 0; mi < 4; mi++)
#pragma unroll
            for (int n = 0; n < 4; n++)
                acc[h * 4 + mi][n] = __builtin_amdgcn_mfma_f32_16x16x32_bf16(
                    bfr[n], af[mi], acc[h * 4 + mi][n], 0, 0, 0);
        __builtin_amdgcn_s_setprio(0);
        __builtin_amdgcn_sched_barrier(0);
    };

    // prologue: stage tile 0 (all 4 slots), drain, barrier
    STAGE(0, 0); STAGE(0, 1); STAGE(0, 2); STAGE(0, 3);
    wait_vm0();
    barrier_();

    const int NT = K >> 6;
    for (int t = 0; t < NT; ++t) {
        const bool pf = (t + 1 < NT);
        // ---- p0: ks0, Mlo | stage A0,A1(t+1) ----
        LDB(t, 0); LDA(t, 0, 0);
        if (pf) { STAGE(t + 1, 0); STAGE(t + 1, 1); }
        barrier_();
        wait_lgkm0();
        MM(0);
        barrier_();
        // ---- p1: ks0, Mhi | stage B0,B1(t+1) ----
        LDA(t, 0, 1);
        if (pf) { STAGE(t + 1, 2); STAGE(t + 1, 3); }
        barrier_();
        wait_lgkm0();
        MM(1);
        barrier_();
        // ---- p2: ks1, Mlo ----
        LDB(t, 1); LDA(t, 1, 0);
        barrier_();
        wait_lgkm0();
        MM(0);
        barrier_();
        // ---- p3: ks1, Mhi | late-issued drain of t+1 stages ----
        LDA(t, 1, 1);
        if (pf) wait_vm0();
        barrier_();
        wait_lgkm0();
        MM(1);
        barrier_();
    }

    // ---- epilogue (validated 2Mx4N scheme): per-wave 16KB LDS C-stage ----
    const int rowbase = bm * 256 + wm * 128;
    const int cb0 = bn * 256 + wn * 64;
    const bool f32p = (MODE == 1) && (cb0 >= 512) && (cb0 < 1024);

    if (!f32p) {
        bf16* cw = lds + wave * 8192;   // [128 rows][64 cols] bf16
        bf16* outp; int cb;
        if (MODE == 1) {
            if (cb0 < 512) { outp = Dbf;  cb = cb0; }
            else           { outp = Dbf2; cb = cb0 - 1024; }
        } else { outp = Dbf; cb = cb0; }
#pragma unroll
        for (int ni = 0; ni < 4; ++ni) {
            const f32x4 bv = *(const f32x4*)(bias + cb0 + ni * 16 + lq * 4);
#pragma unroll
            for (int mi = 0; mi < 8; ++mi) {
                f32x4 v = acc[mi][ni];
                int row = mi * 16 + lr;
                int sl = (ni * 2 + (lq >> 1)) ^ (row & 7);
                bf16x4 o4;
#pragma unroll
                for (int r = 0; r < 4; r++) {
                    float x = v[r] + bv[r];
                    o4[r] = (bf16)(x > 0.f ? x : 0.f);
                }
                *(bf16x4*)(cw + row * 64 + sl * 8 + (lq & 1) * 4) = o4;
            }
        }
#pragma unroll
        for (int it = 0; it < 16; ++it) {
            int g = it * 64 + lane;
            int row = g >> 3, k = g & 7;
            bf16x8 v = *(const bf16x8*)(cw + row * 64 + ((k ^ (row & 7)) * 8));
            *(bf16x8*)(outp + (unsigned)(rowbase + row) * 512u + cb + k * 8) = v;
        }
    } else {
        float* cwf = (float*)(lds + wave * 8192);   // [64 rows][64 f32] x2
        const int cbf = cb0 - 512;
#pragma unroll
        for (int mh = 0; mh < 2; ++mh) {
#pragma unroll
            for (int ni = 0; ni < 4; ++ni) {
                const f32x4 bv = *(const f32x4*)(bias + cb0 + ni * 16 + lq * 4);
#pragma unroll
                for (int mi2 = 0; mi2 < 4; ++mi2) {
                    f32x4 v = acc[mh * 4 + mi2][ni];
                    int row = mi2 * 16 + lr;   // 0..63
                    int s16 = ni * 4 + lq;
                    int sl = (s16 & 8) | ((s16 & 7) ^ (row & 7));
                    f32x4 x;
#pragma unroll
                    for (int r = 0; r < 4; r++) {
                        float tt = v[r] + bv[r];
                        x[r] = tt > 0.f ? tt : 0.f;
                    }
                    *(f32x4*)(cwf + row * 64 + sl * 4) = x;
                }
            }
#pragma unroll
            for (int it = 0; it < 16; ++it) {
                int flat = it * 64 + lane;
                int row = flat >> 4, k = flat & 15;
                int kk = (k & 8) | ((k & 7) ^ (row & 7));
                f32x4 v = *(const f32x4*)(cwf + row * 64 + kk * 4);
                *(f32x4*)(Df + (unsigned)(rowbase + mh * 64 + row) * 512u
                          + cbf + k * 4) = v;
            }
            if (mh == 0) wait_lgkm0();  // WAR: half1 writes reuse half0 space
        }
    }
}

// ============================================================================
// Verified 128x128 4-wave kernel (round-4), for the small gemms 3/4.
// MODE 2: plain -> Dbf.  MODE 3: plain -> Df (f32)
// ============================================================================
template<int MODE, int NBN>
__global__ __launch_bounds__(256, 2) void gemm_k(
    const bf16* __restrict__ A, const bf16* __restrict__ Bt,
    const float* __restrict__ bias, bf16* __restrict__ Dbf,
    float* __restrict__ Df, int K)
{
    const int tid = threadIdx.x;
    const int id = blockIdx.x;
    const int bn = (id >> 3) % NBN;
    const int bm = (id & 7) + 8 * ((id >> 3) / NBN);

    __shared__ __align__(16) bf16 lds[2 * 128 * 64];
    bf16* ldsA = lds;
    bf16* ldsB = lds + 128 * 64;

    const int g_slot = tid & 7;
    const int row0 = tid >> 3;

    unsigned offA[4], offB[4];
#pragma unroll
    for (int i = 0; i < 4; i++) {
        int r = row0 + 32 * i;
        offA[i] = (unsigned)(bm * 128 + r) * (unsigned)K;
        offB[i] = (unsigned)(bn * 128 + r) * (unsigned)K;
    }

    f32x4 acc[4][4];
    const f32x4 zero4 = {0.f, 0.f, 0.f, 0.f};
#pragma unroll
    for (int i = 0; i < 4; i++)
#pragma unroll
        for (int j = 0; j < 4; j++) acc[i][j] = zero4;

    const int wave = tid >> 6;
    const int lane = tid & 63;
    const int wr = (wave >> 1) * 64;
    const int wc = (wave & 1) * 64;
    const int lq = lane >> 4;
    const int lr = lane & 15;

    const int KT = K >> 6;
    for (int kt = 0; kt < KT; ++kt) {
        __syncthreads();
#pragma unroll
        for (int i = 0; i < 4; i++) {
            int r = row0 + 32 * i;
            int gsrc = g_slot ^ (r & 7);
            async_ld16(A + offA[i] + (unsigned)(kt * 64 + gsrc * 8),
                       ldsA + (tid + i * 256) * 8);
        }
#pragma unroll
        for (int i = 0; i < 4; i++) {
            int r = row0 + 32 * i;
            int gsrc = g_slot ^ (r & 7);
            async_ld16(Bt + offB[i] + (unsigned)(kt * 64 + gsrc * 8),
                       ldsB + (tid + i * 256) * 8);
        }
        __syncthreads();

#pragma unroll
        for (int ks = 0; ks < 2; ++ks) {
            bf16x8 af[4], bfr[4];
#pragma unroll
            for (int mi = 0; mi < 4; ++mi) {
                int r = wr + mi * 16 + lr;
                int g = (ks * 4 + lq) ^ (r & 7);
                af[mi] = *(const bf16x8*)(ldsA + (r * 8 + g) * 8);
            }
#pragma unroll
            for (int ni = 0; ni < 4; ++ni) {
                int r = wc + ni * 16 + lr;
                int g = (ks * 4 + lq) ^ (r & 7);
                bfr[ni] = *(const bf16x8*)(ldsB + (r * 8 + g) * 8);
            }
#pragma unroll
            for (int mi = 0; mi < 4; ++mi)
#pragma unroll
                for (int ni = 0; ni < 4; ++ni)
                    acc[mi][ni] = __builtin_amdgcn_mfma_f32_16x16x32_bf16(
                        bfr[ni], af[mi], acc[mi][ni], 0, 0, 0);
        }
    }

    __syncthreads();
    const int rb = bm * 128 + wr;

    if (MODE == 2) {
        bf16* cw = lds + wave * 4096;
        const int cb = bn * 128 + wc;
#pragma unroll
        for (int ni = 0; ni < 4; ++ni) {
            const f32x4 bv = *(const f32x4*)(bias + cb + ni * 16 + lq * 4);
#pragma unroll
            for (int mi = 0; mi < 4; ++mi) {
                f32x4 v = acc[mi][ni];
                int row = mi * 16 + lr;
                int sl = (ni * 2 + (lq >> 1)) ^ (row & 7);
                bf16x4 o4;
#pragma unroll
                for (int r = 0; r < 4; r++) {
                    float t = v[r] + bv[r];
                    o4[r] = (bf16)(t > 0.f ? t : 0.f);
                }
                *(bf16x4*)(cw + row * 64 + sl * 8 + (lq & 1) * 4) = o4;
            }
        }
#pragma unroll
        for (int it = 0; it < 8; ++it) {
            int g = it * 64 + lane;
            int row = g >> 3, k = g & 7;
            bf16x8 v = *(const bf16x8*)(cw + row * 64 + ((k ^ (row & 7)) * 8));
            *(bf16x8*)(Dbf + (unsigned)(rb + row) * 512u + cb + k * 8) = v;
        }
    } else {
        float* cwf = (float*)lds + wave * 2048;
        const int cbf = bn * 128 + wc;
#pragma unroll
        for (int half = 0; half < 2; ++half) {
#pragma unroll
            for (int ni = 0; ni < 4; ++ni) {
                const f32x4 bv = *(const f32x4*)(bias + cbf + ni * 16 + lq * 4);
#pragma unroll
                for (int mi2 = 0; mi2 < 2; ++mi2) {
                    f32x4 v = acc[half * 2 + mi2][ni];
                    int row = mi2 * 16 + lr;
                    int s16 = ni * 4 + lq;
                    int sl = (s16 & 8) | ((s16 & 7) ^ (row & 7));
                    f32x4 x;
#pragma unroll
                    for (int r = 0; r < 4; r++) {
                        float t = v[r] + bv[r];
                        x[r] = t > 0.f ? t : 0.f;
                    }
                    *(f32x4*)(cwf + row * 64 + sl * 4) = x;
                }
            }
#pragma unroll
            for (int it = 0; it < 8; ++it) {
                int g = it * 64 + lane;
                int row = g >> 4, k = g & 15;
                int kk = (k & 8) | ((k & 7) ^ (row & 7));
                f32x4 v = *(const f32x4*)(cwf + row * 64 + kk * 4);
                *(f32x4*)(Df + (unsigned)(rb + half * 32 + row) * 512u + cbf + k * 4) = v;
            }
        }
    }
}

// Fused preprocessing: cvt obj/pred f32->bf16 + 4 weight transposes
__global__ void pre_k(const float4* __restrict__ o, const float4* __restrict__ p,
                      bf16x4* __restrict__ ob, bf16x4* __restrict__ pb,
                      const float* __restrict__ w1, bf16* __restrict__ w1t,
                      const float* __restrict__ w2, bf16* __restrict__ w2t,
                      const float* __restrict__ w3, bf16* __restrict__ w3t,
                      const float* __restrict__ w4, bf16* __restrict__ w4t) {
    __shared__ float tile[32][33];
    int blk = blockIdx.x;
    int t = threadIdx.x;
    if (blk >= 24576) {
        int id = blk - 24576;
        const float* src; bf16* dst; int R, C, bx, by;
        if (id < 768)       { src = w1; dst = w1t; R = 1536; C = 512;  bx = id % 16; by = id / 16; }
        else if (id < 1536) { id -= 768;  src = w2; dst = w2t; R = 512; C = 1536; bx = id % 48; by = id / 48; }
        else if (id < 1792) { id -= 1536; src = w3; dst = w3t; R = 512; C = 512;  bx = id % 16; by = id / 16; }
        else                { id -= 1792; src = w4; dst = w4t; R = 512; C = 512;  bx = id % 16; by = id / 16; }
        int c0 = bx * 32, r0 = by * 32;
        int tx = t & 31, ty = t >> 5;
#pragma unroll
        for (int i = 0; i < 4; i++)
            tile[ty + i * 8][tx] = src[(size_t)(r0 + ty + i * 8) * C + c0 + tx];
        __syncthreads();
#pragma unroll
        for (int i = 0; i < 4; i++)
            dst[(size_t)(c0 + ty + i * 8) * R + r0 + tx] = (bf16)tile[tx][ty + i * 8];
        return;
    }
    int i = blk * 256 + t;
    if (i < 2097152) {
        float4 v = o[i];
        bf16x4 r = { (bf16)v.x, (bf16)v.y, (bf16)v.z, (bf16)v.w };
        ob[i] = r;
    } else {
        int j = i - 2097152;
        float4 v = p[j];
        bf16x4 r = { (bf16)v.x, (bf16)v.y, (bf16)v.z, (bf16)v.w };
        pb[j] = r;
    }
}

// Self-contained scatter-mean pooling (one block per (b,n)).
// 2-way unrolled gather loop: independent row loads + dual accumulators
// (free MLP on the ~4-entry average list).
__global__ __launch_bounds__(256) void pool3_k(
    const int* __restrict__ edges,
    const bf16* __restrict__ new_s, const bf16* __restrict__ new_o,
    bf16* __restrict__ out)
{
    __shared__ int ent[1024];
    __shared__ int ec;
    const int idx = blockIdx.x;
    const int b = idx >> 8, n = idx & 255;
    const int t = threadIdx.x;
    if (t == 0) ec = 0;
    __syncthreads();
#pragma unroll
    for (int e0 = 0; e0 < 2; e0++) {
        int row = b * 512 + t + e0 * 256;
        int s = edges[row * 3 + 0] & 255;
        int o = edges[row * 3 + 2] & 255;
        if (s == n) { int ps = atomicAdd(&ec, 1); ent[ps] = row << 1; }
        if (o == n) { int po = atomicAdd(&ec, 1); ent[po] = (row << 1) | 1; }
    }
    __syncthreads();
    const int c = ec;
    float a0 = 0.f, a1 = 0.f, c0 = 0.f, c1 = 0.f;
    int j = 0;
    for (; j + 1 < c; j += 2) {
        int v0 = ent[j], v1 = ent[j + 1];
        const bf16x2* r0 = (const bf16x2*)(((v0 & 1) ? new_o : new_s) +
                                           (unsigned)(v0 >> 1) * 512u);
        const bf16x2* r1 = (const bf16x2*)(((v1 & 1) ? new_o : new_s) +
                                           (unsigned)(v1 >> 1) * 512u);
        bf16x2 w0 = r0[t];
        bf16x2 w1 = r1[t];
        a0 += (float)w0[0];
        a1 += (float)w0[1];
        c0 += (float)w1[0];
        c1 += (float)w1[1];
    }
    if (j < c) {
        int v = ent[j];
        const bf16x2* rp = (const bf16x2*)(((v & 1) ? new_o : new_s) +
                                           (unsigned)(v >> 1) * 512u);
        bf16x2 w = rp[t];
        a0 += (float)w[0];
        a1 += (float)w[1];
    }
    a0 += c0;
    a1 += c1;
    float inv = 1.f / (float)(c > 1 ? c : 1);
    bf16x2 o2 = { (bf16)(a0 * inv), (bf16)(a1 * inv) };
    *(bf16x2*)(out + (unsigned)idx * 512u + (unsigned)(t * 2)) = o2;
}

extern "C" void kernel_launch(void* const* d_in, const int* in_sizes, int n_in,
                              void* d_out, int out_size, void* d_ws, size_t ws_size,
                              hipStream_t stream) {
    const float* obj_f  = (const float*)d_in[0];
    const float* pred_f = (const float*)d_in[1];
    const int*   edges  = (const int*)d_in[2];
    const float* w1 = (const float*)d_in[3];
    const float* b1 = (const float*)d_in[4];
    const float* w2 = (const float*)d_in[5];
    const float* b2 = (const float*)d_in[6];
    const float* w3 = (const float*)d_in[7];
    const float* b3 = (const float*)d_in[8];
    const float* w4 = (const float*)d_in[9];
    const float* b4 = (const float*)d_in[10];

    // workspace layout — 88 MB
    char* ws = (char*)d_ws;
    bf16* obj_bf  = (bf16*)(ws + 0);            // 16 MB   [dead after gemm1]
    bf16* pred_bf = (bf16*)(ws + 16777216);     // 32 MB   [dead after gemm1]
    bf16* new_s   = (bf16*)(ws + 0);            // 32 MB   overlays obj/pred
    bf16* w1t = (bf16*)(ws + 50331648);         // 512 x 1536
    bf16* w2t = (bf16*)(ws + 51904512);         // 1536 x 512
    bf16* w3t = (bf16*)(ws + 53477376);         // 512 x 512
    bf16* w4t = (bf16*)(ws + 54001664);         // 512 x 512
    bf16* hid = (bf16*)(ws + 54525952);         // 32768 x 512 (32 MB)
    bf16* pooled_bf = hid;                      // 16 MB, reuse after gemm2
    bf16* h2  = (bf16*)(ws + 71303168);         // 16 MB

    float* out_obj = (float*)d_out;             // 64*256*512 f32
    float* out_p   = (float*)d_out + 8388608;   // 64*512*512 f32
    bf16* new_o    = (bf16*)d_out;              // scratch; overwritten by gemm4

    pre_k<<<26624, 256, 0, stream>>>((const float4*)obj_f, (const float4*)pred_f,
                                     (bf16x4*)obj_bf, (bf16x4*)pred_bf,
                                     w1, w1t, w2, w2t, w3, w3t, w4, w4t);

    // gemm1: gathered [obj[s]|pred|obj[o]] (K=1536) -> hid   (256x256, 2Mx4N)
    gemm8_k<0><<<256, 512, 0, stream>>>(
        nullptr, w1t, b1, hid, nullptr, nullptr, edges, obj_bf, pred_bf,
        1536, 2);

    // gemm2: hid @ w2t -> new_s | out_p | new_o              (256x256, 2Mx4N)
    gemm8_k<1><<<768, 512, 0, stream>>>(
        hid, w2t, b2, new_s, out_p, new_o, nullptr, nullptr, nullptr,
        512, 6);

    pool3_k<<<16384, 256, 0, stream>>>(edges, new_s, new_o, pooled_bf);

    // gemm3: pooled @ w3t -> h2   (128x128 path)
    gemm_k<2, 4><<<512, 256, 0, stream>>>(pooled_bf, w3t, b3, h2, nullptr, 512);

    // gemm4: h2 @ w4t -> out_obj (f32)
    gemm_k<3, 4><<<512, 256, 0, stream>>>(h2, w4t, b4, nullptr, out_obj, 512);
}

// Round 14
// 348.642 us; speedup vs baseline: 1.0496x; 1.0007x over previous
//
#include <hip/hip_runtime.h>

typedef __bf16 bf16;
typedef __attribute__((ext_vector_type(2))) __bf16 bf16x2;
typedef __attribute__((ext_vector_type(4))) __bf16 bf16x4;
typedef __attribute__((ext_vector_type(8))) __bf16 bf16x8;
typedef __attribute__((ext_vector_type(4))) float f32x4;

#define DEVINL __device__ __forceinline__

typedef __attribute__((address_space(1))) void gvoid_t;
typedef __attribute__((address_space(3))) void lvoid_t;

DEVINL void async_ld16(const void* g, void* l) {
    __builtin_amdgcn_global_load_lds((gvoid_t*)g, (lvoid_t*)l, 16, 0, 0);
}

DEVINL void wait_vm0()   { asm volatile("s_waitcnt vmcnt(0)" ::: "memory"); }
DEVINL void wait_lgkm0() { asm volatile("s_waitcnt lgkmcnt(0)" ::: "memory");
                           __builtin_amdgcn_sched_barrier(0); }
DEVINL void barrier_()   { __builtin_amdgcn_s_barrier();
                           __builtin_amdgcn_sched_barrier(0); }

// ============================================================================
// 8-wave 256x256 GEMM, 4-phase, 2Mx4N — BEST VERIFIED schedule (r10/r13:
// 348.9 us total, gemm2 74 us @ MfmaUtil 28%, VGPR 100, no spill).
// Schedule-sweep record: seven variants (2-barrier 128², exposed/hidden
// 4-phase, 1Mx8N, 2Mx4N dbuf-vm0, quad-buffer counted-vmcnt) all land at
// 25-29% MfmaUtil on these shapes — structural plateau; do not re-litigate.
// NEW this round (MODE 0 only): obj/pred f32->bf16 conversion FUSED into
// gemm1's A-staging (removes pre_k's 144MB cvt pass, ~25-30 us):
//   A gathered as f32 via reg-staging (T14 split): float4 loads issued at
//   p1/p2, vmcnt(0)+cvt+ds_write at p3 (where the verified schedule already
//   drains vmcnt). B (w1t, bf16) stays on async global_load_lds.
//   fA[8] float4 = +32 arch VGPR peak (p2->p3) — tripwire: spill shows as
//   FETCH/WRITE inflation on gemm1.
// Phases per K-tile t: p0=(ks0,Mlo) p1=(ks0,Mhi) p2=(ks1,Mlo) p3=(ks1,Mhi);
// MODE 0 staging of t+1: B-async at p0, A-f32-loads at p1/p2, cvt+write p3.
// MODE!=0 staging of t+1: A-async at p0, B-async at p1; vm0 at p3.
// LDS = 8 half-slots x 16KB: slot = (t&1)*4 + kind,
//   kind: 0=A rows[0,128), 1=A rows[128,256), 2=B rows[0,128), 3=B rows[128,256)
// Half-slot: [128 rows][8 granules 16B], swizzled: (r,g) holds granule g^(r&7).
// Hazards (re-verified): p3 writes target tile-(t+1) parity (disjoint from
// t's reads); lgkm0 after writes precedes the barrier releasing t+1 readers;
// vm0 at p3 drains B-asyncs (needed at t+1 p0 anyway) + f32 loads (2-phase
// ~600cy margin, sources L2/L3-warm).
// MODE 0: A gathered f32 from obj/pred via edges (K=1536, S|P|O) -> Dbf
// MODE 1: wave-uniform split by col: <512 Dbf | <1024 Df(f32) | else Dbf2
// Epilogue: validated 2Mx4N per-wave 16KB LDS C-stage, full-line copy-out.
// ============================================================================
template<int MODE>
__global__ __launch_bounds__(512, 1) void gemm8_k(
    const bf16* __restrict__ A, const bf16* __restrict__ Bt,
    const float* __restrict__ bias, bf16* __restrict__ Dbf,
    float* __restrict__ Df, bf16* __restrict__ Dbf2,
    const int* __restrict__ edges, const float* __restrict__ objf,
    const float* __restrict__ predf, int K, int NBN)
{
    const int tid = threadIdx.x;
    const int id = blockIdx.x;
    const int bn = (id >> 3) % NBN;
    const int bm = (id & 7) + 8 * ((id >> 3) / NBN);

    __shared__ __align__(16) bf16 lds[8 * 8192];   // 128 KiB

    const int g_slot = tid & 7;
    const int row0 = tid >> 3;   // 0..63

    // staged rows per thread: hi = h*2+i -> row (h*128 + i*64 + row0)
    unsigned offS[4], offP[4], offO[4], offA[4], offB[4];
#pragma unroll
    for (int hi = 0; hi < 4; hi++) {
        int r = (hi >> 1) * 128 + (hi & 1) * 64 + row0;
        int gr = bm * 256 + r;
        if (MODE == 0) {
            int b = gr >> 9;  // T = 512
            int s = edges[gr * 3 + 0] & 255;
            int o = edges[gr * 3 + 2] & 255;
            offS[hi] = (unsigned)(b * 256 + s) * 512u;
            offP[hi] = (unsigned)gr * 512u;
            offO[hi] = (unsigned)(b * 256 + o) * 512u;
        } else {
            offA[hi] = (unsigned)gr * (unsigned)K;
        }
        offB[hi] = (unsigned)(bn * 256 + r) * (unsigned)K;
    }

    // async staging (bf16 sources): kind<2 = A (MODE!=0), kind>=2 = B
    auto STAGE = [&](int tt, int kind) {
        bf16* ldst = lds + ((tt & 1) * 4 + kind) * 8192;
        int h = kind & 1;
#pragma unroll
        for (int i = 0; i < 2; i++) {
            int r = i * 64 + row0;
            int gsrc = g_slot ^ (r & 7);
            int hi = h * 2 + i;
            const bf16* gp;
            if (kind < 2) {
                gp = A + offA[hi] + (unsigned)(tt * 64 + gsrc * 8);
            } else {
                gp = Bt + offB[hi] + (unsigned)(tt * 64 + gsrc * 8);
            }
            async_ld16(gp, ldst + (tid + i * 512) * 8);
        }
    };

    // MODE 0: reg-staged f32 A gather (fused cvt). fA indices are
    // compile-time after inlining+unroll (rule 20).
    float4 fA[8];
    auto A_LOAD = [&](int tt, int kind) {
#pragma unroll
        for (int i = 0; i < 2; i++) {
            int r = i * 64 + row0;
            int gsrc = g_slot ^ (r & 7);
            int hi = kind * 2 + i;
            int region = tt >> 3;   // wave-uniform: 0=S, 1=P, 2=O
            unsigned col = (unsigned)((tt & 7) * 64 + gsrc * 8);
            const float* gp;
            if (region == 0)      gp = objf + offS[hi] + col;
            else if (region == 1) gp = predf + offP[hi] + col;
            else                  gp = objf + offO[hi] + col;
            fA[kind * 4 + i * 2 + 0] = *(const float4*)gp;
            fA[kind * 4 + i * 2 + 1] = *(const float4*)(gp + 4);
        }
    };
    auto A_WRITE = [&](int tt, int kind) {
        bf16* ldst = lds + ((tt & 1) * 4 + kind) * 8192;
#pragma unroll
        for (int i = 0; i < 2; i++) {
            float4 v0 = fA[kind * 4 + i * 2 + 0];
            float4 v1 = fA[kind * 4 + i * 2 + 1];
            bf16x8 w;
            w[0] = (bf16)v0.x; w[1] = (bf16)v0.y;
            w[2] = (bf16)v0.z; w[3] = (bf16)v0.w;
            w[4] = (bf16)v1.x; w[5] = (bf16)v1.y;
            w[6] = (bf16)v1.z; w[7] = (bf16)v1.w;
            *(bf16x8*)(ldst + (tid + i * 512) * 8) = w;
        }
    };

    f32x4 acc[8][4];
    const f32x4 zero4 = {0.f, 0.f, 0.f, 0.f};
#pragma unroll
    for (int i = 0; i < 8; i++)
#pragma unroll
        for (int j = 0; j < 4; j++) acc[i][j] = zero4;

    const int wave = tid >> 6, lane = tid & 63;
    const int wm = wave >> 2, wn = wave & 3;   // 2M x 4N
    const int lq = lane >> 4, lr = lane & 15;

    bf16x8 bfr[4];   // wave's 64 cols, one kstep (K=32); live for 2 phases
    bf16x8 af[4];    // one 64-row M-half, one kstep; reloaded per phase

    auto LDB = [&](int tt, int ks) {
        const bf16* base = lds + ((tt & 1) * 4 + 2 + (wn >> 1)) * 8192;
#pragma unroll
        for (int n = 0; n < 4; n++) {
            int rr = (wn & 1) * 64 + n * 16 + lr;   // local row in B half-slot
            int g = (ks * 4 + lq) ^ (rr & 7);
            bfr[n] = *(const bf16x8*)(base + (rr * 8 + g) * 8);
        }
    };
    auto LDA = [&](int tt, int ks, int h) {
        const bf16* base = lds + ((tt & 1) * 4 + wm) * 8192;
#pragma unroll
        for (int mi = 0; mi < 4; mi++) {
            int rr = (h * 4 + mi) * 16 + lr;        // local row in A half-slot
            int g = (ks * 4 + lq) ^ (rr & 7);
            af[mi] = *(const bf16x8*)(base + (rr * 8 + g) * 8);
        }
    };
    auto MM = [&](int h) {
        __builtin_amdgcn_s_setprio(1);
#pragma unroll
        for (int mi = 0; mi < 4; mi++)
#pragma unroll
            for (int n = 0; n < 4; n++)
                acc[h * 4 + mi][n] = __builtin_amdgcn_mfma_f32_16x16x32_bf16(
                    bfr[n], af[mi], acc[h * 4 + mi][n], 0, 0, 0);
        __builtin_amdgcn_s_setprio(0);
        __builtin_amdgcn_sched_barrier(0);
    };

    // prologue: stage tile 0
    if (MODE == 0) {
        STAGE(0, 2); STAGE(0, 3);        // B async
        A_LOAD(0, 0); A_LOAD(0, 1);      // A f32 gather
        wait_vm0();                      // B-async + f32 loads
        A_WRITE(0, 0); A_WRITE(0, 1);    // cvt + ds_write
        wait_lgkm0();                    // writes visible before barrier
    } else {
        STAGE(0, 0); STAGE(0, 1); STAGE(0, 2); STAGE(0, 3);
        wait_vm0();
    }
    barrier_();

    const int NT = K >> 6;
    for (int t = 0; t < NT; ++t) {
        const bool pf = (t + 1 < NT);
        // ---- p0: ks0, Mlo ----
        LDB(t, 0); LDA(t, 0, 0);
        if (pf) {
            if (MODE == 0) { STAGE(t + 1, 2); STAGE(t + 1, 3); }  // B async
            else           { STAGE(t + 1, 0); STAGE(t + 1, 1); }  // A async
        }
        barrier_();
        wait_lgkm0();
        MM(0);
        barrier_();
        // ---- p1: ks0, Mhi ----
        LDA(t, 0, 1);
        if (pf) {
            if (MODE == 0) A_LOAD(t + 1, 0);                       // A0 f32
            else           { STAGE(t + 1, 2); STAGE(t + 1, 3); }   // B async
        }
        barrier_();
        wait_lgkm0();
        MM(1);
        barrier_();
        // ---- p2: ks1, Mlo ----
        LDB(t, 1); LDA(t, 1, 0);
        if (pf && MODE == 0) A_LOAD(t + 1, 1);                     // A1 f32
        barrier_();
        wait_lgkm0();
        MM(0);
        barrier_();
        // ---- p3: ks1, Mhi | drain + (MODE 0) cvt+write A(t+1) ----
        LDA(t, 1, 1);
        if (pf) {
            wait_vm0();
            if (MODE == 0) { A_WRITE(t + 1, 0); A_WRITE(t + 1, 1); }
        }
        barrier_();
        wait_lgkm0();
        MM(1);
        barrier_();
    }

    // ---- epilogue (validated 2Mx4N scheme): per-wave 16KB LDS C-stage ----
    const int rowbase = bm * 256 + wm * 128;
    const int cb0 = bn * 256 + wn * 64;
    const bool f32p = (MODE == 1) && (cb0 >= 512) && (cb0 < 1024);

    if (!f32p) {
        bf16* cw = lds + wave * 8192;   // [128 rows][64 cols] bf16
        bf16* outp; int cb;
        if (MODE == 1) {
            if (cb0 < 512) { outp = Dbf;  cb = cb0; }
            else           { outp = Dbf2; cb = cb0 - 1024; }
        } else { outp = Dbf; cb = cb0; }
#pragma unroll
        for (int ni = 0; ni < 4; ++ni) {
            const f32x4 bv = *(const f32x4*)(bias + cb0 + ni * 16 + lq * 4);
#pragma unroll
            for (int mi = 0; mi < 8; ++mi) {
                f32x4 v = acc[mi][ni];
                int row = mi * 16 + lr;
                int sl = (ni * 2 + (lq >> 1)) ^ (row & 7);
                bf16x4 o4;
#pragma unroll
                for (int r = 0; r < 4; r++) {
                    float x = v[r] + bv[r];
                    o4[r] = (bf16)(x > 0.f ? x : 0.f);
                }
                *(bf16x4*)(cw + row * 64 + sl * 8 + (lq & 1) * 4) = o4;
            }
        }
#pragma unroll
        for (int it = 0; it < 16; ++it) {
            int g = it * 64 + lane;
            int row = g >> 3, k = g & 7;
            bf16x8 v = *(const bf16x8*)(cw + row * 64 + ((k ^ (row & 7)) * 8));
            *(bf16x8*)(outp + (unsigned)(rowbase + row) * 512u + cb + k * 8) = v;
        }
    } else {
        float* cwf = (float*)(lds + wave * 8192);   // [64 rows][64 f32] x2
        const int cbf = cb0 - 512;
#pragma unroll
        for (int mh = 0; mh < 2; ++mh) {
#pragma unroll
            for (int ni = 0; ni < 4; ++ni) {
                const f32x4 bv = *(const f32x4*)(bias + cb0 + ni * 16 + lq * 4);
#pragma unroll
                for (int mi2 = 0; mi2 < 4; ++mi2) {
                    f32x4 v = acc[mh * 4 + mi2][ni];
                    int row = mi2 * 16 + lr;   // 0..63
                    int s16 = ni * 4 + lq;
                    int sl = (s16 & 8) | ((s16 & 7) ^ (row & 7));
                    f32x4 x;
#pragma unroll
                    for (int r = 0; r < 4; r++) {
                        float tt = v[r] + bv[r];
                        x[r] = tt > 0.f ? tt : 0.f;
                    }
                    *(f32x4*)(cwf + row * 64 + sl * 4) = x;
                }
            }
#pragma unroll
            for (int it = 0; it < 16; ++it) {
                int flat = it * 64 + lane;
                int row = flat >> 4, k = flat & 15;
                int kk = (k & 8) | ((k & 7) ^ (row & 7));
                f32x4 v = *(const f32x4*)(cwf + row * 64 + kk * 4);
                *(f32x4*)(Df + (unsigned)(rowbase + mh * 64 + row) * 512u
                          + cbf + k * 4) = v;
            }
            if (mh == 0) wait_lgkm0();  // WAR: half1 writes reuse half0 space
        }
    }
}

// ============================================================================
// Verified 128x128 4-wave kernel (round-4), for the small gemms 3/4.
// MODE 2: plain -> Dbf.  MODE 3: plain -> Df (f32)
// ============================================================================
template<int MODE, int NBN>
__global__ __launch_bounds__(256, 2) void gemm_k(
    const bf16* __restrict__ A, const bf16* __restrict__ Bt,
    const float* __restrict__ bias, bf16* __restrict__ Dbf,
    float* __restrict__ Df, int K)
{
    const int tid = threadIdx.x;
    const int id = blockIdx.x;
    const int bn = (id >> 3) % NBN;
    const int bm = (id & 7) + 8 * ((id >> 3) / NBN);

    __shared__ __align__(16) bf16 lds[2 * 128 * 64];
    bf16* ldsA = lds;
    bf16* ldsB = lds + 128 * 64;

    const int g_slot = tid & 7;
    const int row0 = tid >> 3;

    unsigned offA[4], offB[4];
#pragma unroll
    for (int i = 0; i < 4; i++) {
        int r = row0 + 32 * i;
        offA[i] = (unsigned)(bm * 128 + r) * (unsigned)K;
        offB[i] = (unsigned)(bn * 128 + r) * (unsigned)K;
    }

    f32x4 acc[4][4];
    const f32x4 zero4 = {0.f, 0.f, 0.f, 0.f};
#pragma unroll
    for (int i = 0; i < 4; i++)
#pragma unroll
        for (int j = 0; j < 4; j++) acc[i][j] = zero4;

    const int wave = tid >> 6;
    const int lane = tid & 63;
    const int wr = (wave >> 1) * 64;
    const int wc = (wave & 1) * 64;
    const int lq = lane >> 4;
    const int lr = lane & 15;

    const int KT = K >> 6;
    for (int kt = 0; kt < KT; ++kt) {
        __syncthreads();
#pragma unroll
        for (int i = 0; i < 4; i++) {
            int r = row0 + 32 * i;
            int gsrc = g_slot ^ (r & 7);
            async_ld16(A + offA[i] + (unsigned)(kt * 64 + gsrc * 8),
                       ldsA + (tid + i * 256) * 8);
        }
#pragma unroll
        for (int i = 0; i < 4; i++) {
            int r = row0 + 32 * i;
            int gsrc = g_slot ^ (r & 7);
            async_ld16(Bt + offB[i] + (unsigned)(kt * 64 + gsrc * 8),
                       ldsB + (tid + i * 256) * 8);
        }
        __syncthreads();

#pragma unroll
        for (int ks = 0; ks < 2; ++ks) {
            bf16x8 af[4], bfr[4];
#pragma unroll
            for (int mi = 0; mi < 4; ++mi) {
                int r = wr + mi * 16 + lr;
                int g = (ks * 4 + lq) ^ (r & 7);
                af[mi] = *(const bf16x8*)(ldsA + (r * 8 + g) * 8);
            }
#pragma unroll
            for (int ni = 0; ni < 4; ++ni) {
                int r = wc + ni * 16 + lr;
                int g = (ks * 4 + lq) ^ (r & 7);
                bfr[ni] = *(const bf16x8*)(ldsB + (r * 8 + g) * 8);
            }
#pragma unroll
            for (int mi = 0; mi < 4; ++mi)
#pragma unroll
                for (int ni = 0; ni < 4; ++ni)
                    acc[mi][ni] = __builtin_amdgcn_mfma_f32_16x16x32_bf16(
                        bfr[ni], af[mi], acc[mi][ni], 0, 0, 0);
        }
    }

    __syncthreads();
    const int rb = bm * 128 + wr;

    if (MODE == 2) {
        bf16* cw = lds + wave * 4096;
        const int cb = bn * 128 + wc;
#pragma unroll
        for (int ni = 0; ni < 4; ++ni) {
            const f32x4 bv = *(const f32x4*)(bias + cb + ni * 16 + lq * 4);
#pragma unroll
            for (int mi = 0; mi < 4; ++mi) {
                f32x4 v = acc[mi][ni];
                int row = mi * 16 + lr;
                int sl = (ni * 2 + (lq >> 1)) ^ (row & 7);
                bf16x4 o4;
#pragma unroll
                for (int r = 0; r < 4; r++) {
                    float t = v[r] + bv[r];
                    o4[r] = (bf16)(t > 0.f ? t : 0.f);
                }
                *(bf16x4*)(cw + row * 64 + sl * 8 + (lq & 1) * 4) = o4;
            }
        }
#pragma unroll
        for (int it = 0; it < 8; ++it) {
            int g = it * 64 + lane;
            int row = g >> 3, k = g & 7;
            bf16x8 v = *(const bf16x8*)(cw + row * 64 + ((k ^ (row & 7)) * 8));
            *(bf16x8*)(Dbf + (unsigned)(rb + row) * 512u + cb + k * 8) = v;
        }
    } else {
        float* cwf = (float*)lds + wave * 2048;
        const int cbf = bn * 128 + wc;
#pragma unroll
        for (int half = 0; half < 2; ++half) {
#pragma unroll
            for (int ni = 0; ni < 4; ++ni) {
                const f32x4 bv = *(const f32x4*)(bias + cbf + ni * 16 + lq * 4);
#pragma unroll
                for (int mi2 = 0; mi2 < 2; ++mi2) {
                    f32x4 v = acc[half * 2 + mi2][ni];
                    int row = mi2 * 16 + lr;
                    int s16 = ni * 4 + lq;
                    int sl = (s16 & 8) | ((s16 & 7) ^ (row & 7));
                    f32x4 x;
#pragma unroll
                    for (int r = 0; r < 4; r++) {
                        float t = v[r] + bv[r];
                        x[r] = t > 0.f ? t : 0.f;
                    }
                    *(f32x4*)(cwf + row * 64 + sl * 4) = x;
                }
            }
#pragma unroll
            for (int it = 0; it < 8; ++it) {
                int g = it * 64 + lane;
                int row = g >> 4, k = g & 15;
                int kk = (k & 8) | ((k & 7) ^ (row & 7));
                f32x4 v = *(const f32x4*)(cwf + row * 64 + kk * 4);
                *(f32x4*)(Df + (unsigned)(rb + half * 32 + row) * 512u + cbf + k * 4) = v;
            }
        }
    }
}

// Weight transposes only (obj/pred cvt fused into gemm1): f32 (RxC) -> bf16 (CxR)
__global__ void pre_k(const float* __restrict__ w1, bf16* __restrict__ w1t,
                      const float* __restrict__ w2, bf16* __restrict__ w2t,
                      const float* __restrict__ w3, bf16* __restrict__ w3t,
                      const float* __restrict__ w4, bf16* __restrict__ w4t) {
    __shared__ float tile[32][33];
    int id = blockIdx.x;
    int t = threadIdx.x;
    const float* src; bf16* dst; int R, C, bx, by;
    if (id < 768)       { src = w1; dst = w1t; R = 1536; C = 512;  bx = id % 16; by = id / 16; }
    else if (id < 1536) { id -= 768;  src = w2; dst = w2t; R = 512; C = 1536; bx = id % 48; by = id / 48; }
    else if (id < 1792) { id -= 1536; src = w3; dst = w3t; R = 512; C = 512;  bx = id % 16; by = id / 16; }
    else                { id -= 1792; src = w4; dst = w4t; R = 512; C = 512;  bx = id % 16; by = id / 16; }
    int c0 = bx * 32, r0 = by * 32;
    int tx = t & 31, ty = t >> 5;  // (32,8)
#pragma unroll
    for (int i = 0; i < 4; i++)
        tile[ty + i * 8][tx] = src[(size_t)(r0 + ty + i * 8) * C + c0 + tx];
    __syncthreads();
#pragma unroll
    for (int i = 0; i < 4; i++)
        dst[(size_t)(c0 + ty + i * 8) * R + r0 + tx] = (bf16)tile[tx][ty + i * 8];
}

// Self-contained scatter-mean pooling (one block per (b,n)).
// 2-way unrolled gather loop: independent row loads + dual accumulators.
__global__ __launch_bounds__(256) void pool3_k(
    const int* __restrict__ edges,
    const bf16* __restrict__ new_s, const bf16* __restrict__ new_o,
    bf16* __restrict__ out)
{
    __shared__ int ent[1024];
    __shared__ int ec;
    const int idx = blockIdx.x;
    const int b = idx >> 8, n = idx & 255;
    const int t = threadIdx.x;
    if (t == 0) ec = 0;
    __syncthreads();
#pragma unroll
    for (int e0 = 0; e0 < 2; e0++) {
        int row = b * 512 + t + e0 * 256;
        int s = edges[row * 3 + 0] & 255;
        int o = edges[row * 3 + 2] & 255;
        if (s == n) { int ps = atomicAdd(&ec, 1); ent[ps] = row << 1; }
        if (o == n) { int po = atomicAdd(&ec, 1); ent[po] = (row << 1) | 1; }
    }
    __syncthreads();
    const int c = ec;
    float a0 = 0.f, a1 = 0.f, c0 = 0.f, c1 = 0.f;
    int j = 0;
    for (; j + 1 < c; j += 2) {
        int v0 = ent[j], v1 = ent[j + 1];
        const bf16x2* r0 = (const bf16x2*)(((v0 & 1) ? new_o : new_s) +
                                           (unsigned)(v0 >> 1) * 512u);
        const bf16x2* r1 = (const bf16x2*)(((v1 & 1) ? new_o : new_s) +
                                           (unsigned)(v1 >> 1) * 512u);
        bf16x2 w0 = r0[t];
        bf16x2 w1 = r1[t];
        a0 += (float)w0[0];
        a1 += (float)w0[1];
        c0 += (float)w1[0];
        c1 += (float)w1[1];
    }
    if (j < c) {
        int v = ent[j];
        const bf16x2* rp = (const bf16x2*)(((v & 1) ? new_o : new_s) +
                                           (unsigned)(v >> 1) * 512u);
        bf16x2 w = rp[t];
        a0 += (float)w[0];
        a1 += (float)w[1];
    }
    a0 += c0;
    a1 += c1;
    float inv = 1.f / (float)(c > 1 ? c : 1);
    bf16x2 o2 = { (bf16)(a0 * inv), (bf16)(a1 * inv) };
    *(bf16x2*)(out + (unsigned)idx * 512u + (unsigned)(t * 2)) = o2;
}

extern "C" void kernel_launch(void* const* d_in, const int* in_sizes, int n_in,
                              void* d_out, int out_size, void* d_ws, size_t ws_size,
                              hipStream_t stream) {
    const float* obj_f  = (const float*)d_in[0];
    const float* pred_f = (const float*)d_in[1];
    const int*   edges  = (const int*)d_in[2];
    const float* w1 = (const float*)d_in[3];
    const float* b1 = (const float*)d_in[4];
    const float* w2 = (const float*)d_in[5];
    const float* b2 = (const float*)d_in[6];
    const float* w3 = (const float*)d_in[7];
    const float* b3 = (const float*)d_in[8];
    const float* w4 = (const float*)d_in[9];
    const float* b4 = (const float*)d_in[10];

    // workspace layout — 88 MB
    char* ws = (char*)d_ws;
    bf16* new_s   = (bf16*)(ws + 0);            // 32 MB
    bf16* w1t = (bf16*)(ws + 50331648);         // 512 x 1536
    bf16* w2t = (bf16*)(ws + 51904512);         // 1536 x 512
    bf16* w3t = (bf16*)(ws + 53477376);         // 512 x 512
    bf16* w4t = (bf16*)(ws + 54001664);         // 512 x 512
    bf16* hid = (bf16*)(ws + 54525952);         // 32768 x 512 (32 MB)
    bf16* pooled_bf = hid;                      // 16 MB, reuse after gemm2
    bf16* h2  = (bf16*)(ws + 71303168);         // 16 MB

    float* out_obj = (float*)d_out;             // 64*256*512 f32
    float* out_p   = (float*)d_out + 8388608;   // 64*512*512 f32
    bf16* new_o    = (bf16*)d_out;              // scratch; overwritten by gemm4

    // weight transposes only (obj/pred conversion fused into gemm1)
    pre_k<<<2048, 256, 0, stream>>>(w1, w1t, w2, w2t, w3, w3t, w4, w4t);

    // gemm1: gathered f32 [obj[s]|pred|obj[o]] (K=1536), fused cvt -> hid
    gemm8_k<0><<<256, 512, 0, stream>>>(
        nullptr, w1t, b1, hid, nullptr, nullptr, edges, obj_f, pred_f,
        1536, 2);

    // gemm2: hid @ w2t -> new_s | out_p | new_o
    gemm8_k<1><<<768, 512, 0, stream>>>(
        hid, w2t, b2, new_s, out_p, new_o, nullptr, nullptr, nullptr,
        512, 6);

    pool3_k<<<16384, 256, 0, stream>>>(edges, new_s, new_o, pooled_bf);

    // gemm3: pooled @ w3t -> h2   (128x128 path)
    gemm_k<2, 4><<<512, 256, 0, stream>>>(pooled_bf, w3t, b3, h2, nullptr, 512);

    // gemm4: h2 @ w4t -> out_obj (f32)
    gemm_k<3, 4><<<512, 256, 0, stream>>>(h2, w4t, b4, nullptr, out_obj, 512);
}